// Round 2
// baseline (707.133 us; speedup 1.0000x reference)
//
#include <hip/hip_runtime.h>
#include <math.h>

typedef unsigned short u16;
typedef __attribute__((ext_vector_type(4))) float f32x4;
typedef __attribute__((ext_vector_type(8))) short bf16x8;
typedef __attribute__((ext_vector_type(4))) unsigned short u16x4;
typedef __attribute__((ext_vector_type(8))) unsigned short u16x8;

#define DEVI static __device__ __forceinline__

DEVI float b2f(u16 u){ union{float f; unsigned i;} v; v.i = ((unsigned)u)<<16; return v.f; }
DEVI u16 f2b(float f){ union{float f; unsigned i;} v; v.f=f;
  unsigned r = v.i + 0x7fffu + ((v.i>>16)&1u); return (u16)(r>>16); }

DEVI void gload_lds16(const void* g, void* l){
  __builtin_amdgcn_global_load_lds((const __attribute__((address_space(1))) void*)g,
                                   (__attribute__((address_space(3))) void*)l, 16, 0, 0);
}

// ---------------------------------------------------------------------------
// W (512x512 f32, row-major [k][c]) -> Wt bf16 [c][k]
__global__ void prepw_k(const float* __restrict__ W, u16* __restrict__ Wt){
  int id = blockIdx.x*256 + threadIdx.x;
  int k = id>>9, c = id&511;
  Wt[c*512 + k] = f2b(W[id]);
}

// f32 [nrows][512] -> bf16 [nrows][512] (+ optional row norms of the bf16 values)
__global__ void cvt_k(const float* __restrict__ src, u16* __restrict__ dst,
                      float* __restrict__ norms, int nrows){
  int gw = (int)((blockIdx.x*blockDim.x + threadIdx.x)>>6);
  int lane = threadIdx.x & 63;
  if (gw >= nrows) return;
  const float* s = src + (size_t)gw*512;
  u16* d = dst + (size_t)gw*512;
  float acc = 0.f;
  #pragma unroll
  for (int q=0;q<2;q++){
    f32x4 v = *(const f32x4*)(s + q*256 + lane*4);
    u16x4 u;
    #pragma unroll
    for (int e=0;e<4;e++){
      u16 b = f2b(v[e]); u[e] = b;
      float fv = b2f(b); acc += fv*fv;
    }
    *(u16x4*)(d + q*256 + lane*4) = u;
  }
  #pragma unroll
  for (int off=1;off<64;off<<=1) acc += __shfl_xor(acc, off);
  if (norms != nullptr && lane==0) norms[gw] = acc;
}

// row norms of a bf16 [nrows][512] matrix
__global__ void normb_k(const u16* __restrict__ src, float* __restrict__ norms, int nrows){
  int gw = (int)((blockIdx.x*blockDim.x + threadIdx.x)>>6);
  int lane = threadIdx.x & 63;
  if (gw >= nrows) return;
  const u16* s = src + (size_t)gw*512;
  u16x8 v = *(const u16x8*)(s + lane*8);
  float acc = 0.f;
  #pragma unroll
  for (int e=0;e<8;e++){ float f = b2f(v[e]); acc += f*f; }
  #pragma unroll
  for (int off=1;off<64;off<<=1) acc += __shfl_xor(acc, off);
  if (lane==0) norms[gw] = acc;
}

// ---------------------------------------------------------------------------
// OUT[r][c] = act(sum_k X[r][k]*W[k][c] + bias[c]) ; X bf16 [R][512], Wt bf16 [c][k]
template<int ACT>
__global__ __launch_bounds__(256) void gemm_k(const u16* __restrict__ X,
    const u16* __restrict__ Wt, const float* __restrict__ bias, u16* __restrict__ OUT){
  __shared__ __align__(16) u16 sA[128*64];
  __shared__ __align__(16) u16 sB[128*64];
  const int tid = threadIdx.x, wave = tid>>6, lane = tid&63;
  // XCD-chunked swizzle: same-rblk blocks land on the same XCD (grid=2048, %8==0)
  const int bid = (blockIdx.x&7)*256 + (blockIdx.x>>3);
  const int rblk = bid>>2, cb = (bid&3)<<7;
  const u16* Xb = X + (size_t)rblk*(128*512);
  const u16* Wb = Wt + (size_t)cb*512;
  const int lrow = lane&15, lg = lane>>4, wr = wave>>1, wc = wave&1;
  f32x4 acc[4][4] = {};
  for (int s=0;s<8;s++){
    const int k0 = s<<6;
    #pragma unroll
    for (int q=0;q<4;q++){
      const int i = (wave<<2)+q;
      const int row = (i<<3) + (lane>>3);
      const int cd = (lane&7) ^ (row&7);
      gload_lds16(Xb + row*512 + k0 + (cd<<3), sA + i*512);
      gload_lds16(Wb + row*512 + k0 + (cd<<3), sB + i*512);
    }
    __syncthreads();
    #pragma unroll
    for (int kh=0;kh<2;kh++){
      bf16x8 a_[4], b_[4];
      #pragma unroll
      for (int i=0;i<4;i++){
        const int ra = (wr<<6)+(i<<4)+lrow;
        a_[i] = *(const bf16x8*)(sA + ra*64 + ((((kh<<2)+lg)^(ra&7))<<3));
        const int rb = (wc<<6)+(i<<4)+lrow;
        b_[i] = *(const bf16x8*)(sB + rb*64 + ((((kh<<2)+lg)^(rb&7))<<3));
      }
      #pragma unroll
      for (int i=0;i<4;i++)
        #pragma unroll
        for (int j=0;j<4;j++)
          acc[i][j] = __builtin_amdgcn_mfma_f32_16x16x32_bf16(a_[i], b_[j], acc[i][j], 0,0,0);
    }
    __syncthreads();
  }
  #pragma unroll
  for (int j=0;j<4;j++){
    const int col = cb + (wc<<6) + (j<<4) + lrow;
    const float bv = bias[col];
    #pragma unroll
    for (int i=0;i<4;i++){
      const int row0 = (rblk<<7) + (wr<<6) + (i<<4) + (lg<<2);
      #pragma unroll
      for (int r=0;r<4;r++){
        float v = acc[i][j][r] + bv;
        if (ACT) v = fmaxf(v, 0.f);
        OUT[(size_t)(row0+r)*512 + col] = f2b(v);
      }
    }
  }
}

// OUT[b][k][m] = sqrt(max(na[k]+nb[m]-2*dot(Xa[b][k],Xb[b][m]), 1e-6)); one block/batch
__global__ __launch_bounds__(256) void pdist_k(const u16* __restrict__ Xa,
    const u16* __restrict__ Xb2, const float* __restrict__ na, const float* __restrict__ nb,
    float* __restrict__ OUT){
  __shared__ __align__(16) u16 sA[128*64];
  __shared__ __align__(16) u16 sB[128*64];
  const int tid = threadIdx.x, wave = tid>>6, lane = tid&63;
  const int b = blockIdx.x;
  const u16* Ab = Xa + (size_t)b*(128*512);
  const u16* Bb = Xb2 + (size_t)b*(128*512);
  const int lrow = lane&15, lg = lane>>4, wr = wave>>1, wc = wave&1;
  f32x4 acc[4][4] = {};
  for (int s=0;s<8;s++){
    const int k0 = s<<6;
    #pragma unroll
    for (int q=0;q<4;q++){
      const int i = (wave<<2)+q;
      const int row = (i<<3) + (lane>>3);
      const int cd = (lane&7) ^ (row&7);
      gload_lds16(Ab + row*512 + k0 + (cd<<3), sA + i*512);
      gload_lds16(Bb + row*512 + k0 + (cd<<3), sB + i*512);
    }
    __syncthreads();
    #pragma unroll
    for (int kh=0;kh<2;kh++){
      bf16x8 a_[4], b_[4];
      #pragma unroll
      for (int i=0;i<4;i++){
        const int ra = (wr<<6)+(i<<4)+lrow;
        a_[i] = *(const bf16x8*)(sA + ra*64 + ((((kh<<2)+lg)^(ra&7))<<3));
        const int rb = (wc<<6)+(i<<4)+lrow;
        b_[i] = *(const bf16x8*)(sB + rb*64 + ((((kh<<2)+lg)^(rb&7))<<3));
      }
      #pragma unroll
      for (int i=0;i<4;i++)
        #pragma unroll
        for (int j=0;j<4;j++)
          acc[i][j] = __builtin_amdgcn_mfma_f32_16x16x32_bf16(a_[i], b_[j], acc[i][j], 0,0,0);
    }
    __syncthreads();
  }
  #pragma unroll
  for (int j=0;j<4;j++){
    const int col = (wc<<6)+(j<<4)+lrow;
    const float nbv = nb[b*128+col];
    #pragma unroll
    for (int i=0;i<4;i++){
      const int row0 = (wr<<6)+(i<<4)+(lg<<2);
      #pragma unroll
      for (int r=0;r<4;r++){
        float n2 = na[b*128+row0+r] + nbv - 2.0f*acc[i][j][r];
        OUT[(size_t)b*16384 + (size_t)(row0+r)*128 + col] = sqrtf(fmaxf(n2, 1e-6f));
      }
    }
  }
}

// ---------------------------------------------------------------------------
// mu/nu + their logs. 256 blocks x 128 threads.
__global__ void prep_k(const float* __restrict__ mask_q, const float* __restrict__ mask_r,
                       float* __restrict__ lmu, float* __restrict__ lnu,
                       float* __restrict__ mu, float* __restrict__ nu){
  int b = blockIdx.x, t = threadIdx.x;
  __shared__ float red[4];
  float mq = mask_q[b*128+t], mr = mask_r[b*128+t];
  float s1 = mq, s2 = mr;
  #pragma unroll
  for (int off=1;off<64;off<<=1){ s1 += __shfl_xor(s1,off); s2 += __shfl_xor(s2,off); }
  if ((t&63)==0){ red[t>>6] = s1; red[2+(t>>6)] = s2; }
  __syncthreads();
  float sumq = red[0]+red[1], sumr = red[2]+red[3];
  float muv = mq/(sumq+1e-8f), nuv = mr/(sumr+1e-8f);
  lmu[b*128+t] = __logf(fmaxf(muv,1e-8f));
  lnu[b*128+t] = __logf(fmaxf(nuv,1e-8f));
  mu[b*128+t] = muv;
  nu[b*128+t] = nuv;
}

// ---------------------------------------------------------------------------
// The entire 5-iteration FGW outer loop, fused. One block (256 thr) per batch.
// T lives in registers (fragment layout: rows ty+16i, cols 4tx+64j+e).
__global__ __launch_bounds__(256,1) void fgw_loop_k(
    const float* __restrict__ Sq_g, const float* __restrict__ Sr_g,
    const float* __restrict__ C_g,
    const float* __restrict__ MU, const float* __restrict__ NU,
    const float* __restrict__ LMU, const float* __restrict__ LNU,
    const float* __restrict__ log_eps,
    float* __restrict__ T_out, float* __restrict__ cost_out, float* __restrict__ sim_out)
{
  __shared__ __align__(16) float bufX[128*128];   // T, then TSr  (stride 128)
  __shared__ __align__(16) float bufY[128*128];   // Sr, then Sq  (stride 128, linear for gload_lds)
  __shared__ __align__(16) float av[128];
  __shared__ __align__(16) float bv[128];
  __shared__ __align__(16) float lvs[128];
  __shared__ float mus[128], nus[128], lmus[128], lnus[128];
  __shared__ float pb[4][128][2];
  __shared__ float red[4];

  const int b = blockIdx.x, tid = threadIdx.x;
  const int lane = tid&63, wv = tid>>6;
  const int tx = tid&15, ty = tid>>4;
  const float* Sqb = Sq_g + (size_t)b*16384;
  const float* Srb = Sr_g + (size_t)b*16384;
  const float* Cb  = C_g  + (size_t)b*16384;

  float eps = __expf(log_eps[0]); eps = fminf(fmaxf(eps,0.01f),0.5f);
  const float rho = 0.1f/(0.1f+eps), inve = 1.0f/eps;

  if (tid<128){ mus[tid]=MU[b*128+tid]; nus[tid]=NU[b*128+tid];
                lmus[tid]=LMU[b*128+tid]; lnus[tid]=LNU[b*128+tid]; }
  __syncthreads();

  float lmu_r[8];
  #pragma unroll
  for (int i=0;i<8;i++) lmu_r[i] = lmus[ty+16*i];
  const f32x4 nu0  = *(const f32x4*)&nus[4*tx],  nu1  = *(const f32x4*)&nus[64+4*tx];
  const f32x4 lnu0 = *(const f32x4*)&lnus[4*tx], lnu1 = *(const f32x4*)&lnus[64+4*tx];
  (void)lnu0; (void)lnu1;

  // T0 = mu (x) nu
  f32x4 Tf[8][2];
  #pragma unroll
  for (int i=0;i<8;i++){ float m = mus[ty+16*i]; Tf[i][0]=m*nu0; Tf[i][1]=m*nu1; }

  float cost_final = 0.f;

  for (int outer=0; outer<5; outer++){
    // ---- iter prologue: stage Sr -> bufY (async), av/bv from T-regs, dump T -> bufX
    #pragma unroll
    for (int q=0;q<16;q++){
      const int c = wv*16+q;
      gload_lds16(Srb + c*256 + lane*4, (char*)bufY + c*1024);
    }
    #pragma unroll
    for (int i=0;i<8;i++){                 // av = rowsum(T)
      f32x4 s4 = Tf[i][0]+Tf[i][1];
      float s = s4[0]+s4[1]+s4[2]+s4[3];
      s += __shfl_xor(s,1); s += __shfl_xor(s,2); s += __shfl_xor(s,4); s += __shfl_xor(s,8);
      if (tx==0) av[ty+16*i] = s;
    }
    {                                      // bv = colsum(T): wave partials -> pb
      f32x4 p0={0.f,0.f,0.f,0.f}, p1={0.f,0.f,0.f,0.f};
      #pragma unroll
      for (int i=0;i<8;i++){ p0 += Tf[i][0]; p1 += Tf[i][1]; }
      #pragma unroll
      for (int e=0;e<4;e++){
        float v0=p0[e]; v0 += __shfl_xor(v0,16); v0 += __shfl_xor(v0,32);
        float v1=p1[e]; v1 += __shfl_xor(v1,16); v1 += __shfl_xor(v1,32);
        if ((lane>>4)==0){ pb[wv][4*tx+e][0]=v0; pb[wv][64+4*tx+e][0]=v1; }
      }
    }
    #pragma unroll
    for (int i=0;i<8;i++){                 // dump T
      *(f32x4*)&bufX[(ty+16*i)*128 + 4*tx     ] = Tf[i][0];
      *(f32x4*)&bufX[(ty+16*i)*128 + 4*tx + 64] = Tf[i][1];
    }
    __syncthreads();
    if (tid<128) bv[tid] = pb[0][tid][0]+pb[1][tid][0]+pb[2][tid][0]+pb[3][tid][0];
    __syncthreads();

    // ---- phase A: TSr = T @ Sr ; fold t2 = bv @ Sr^2
    f32x4 acc[8][2] = {};
    f32x4 t2p0={0.f,0.f,0.f,0.f}, t2p1={0.f,0.f,0.f,0.f};
    for (int k0=0;k0<128;k0+=4){
      f32x4 a4[8];
      #pragma unroll
      for (int i=0;i<8;i++) a4[i] = *(const f32x4*)&bufX[(ty+16*i)*128 + k0];
      const f32x4 bvv = *(const f32x4*)&bv[k0];
      #pragma unroll
      for (int kk=0;kk<4;kk++){
        const f32x4 b0 = *(const f32x4*)&bufY[(k0+kk)*128 + 4*tx];
        const f32x4 b1 = *(const f32x4*)&bufY[(k0+kk)*128 + 4*tx + 64];
        t2p0 += bvv[kk]*b0*b0; t2p1 += bvv[kk]*b1*b1;
        #pragma unroll
        for (int i=0;i<8;i++){ acc[i][0] += a4[i][kk]*b0; acc[i][1] += a4[i][kk]*b1; }
      }
    }
    __syncthreads();

    // ---- dump TSr -> bufX, stage Sq -> bufY
    #pragma unroll
    for (int q=0;q<16;q++){
      const int c = wv*16+q;
      gload_lds16(Sqb + c*256 + lane*4, (char*)bufY + c*1024);
    }
    #pragma unroll
    for (int i=0;i<8;i++){
      *(f32x4*)&bufX[(ty+16*i)*128 + 4*tx     ] = acc[i][0];
      *(f32x4*)&bufX[(ty+16*i)*128 + 4*tx + 64] = acc[i][1];
    }
    __syncthreads();

    // ---- phase B: G = Sq @ TSr ; fold t1 = Sq^2 @ av
    f32x4 g[8][2] = {};
    f32x4 t1a[8] = {};
    for (int k0=0;k0<128;k0+=4){
      f32x4 a4[8];
      #pragma unroll
      for (int i=0;i<8;i++) a4[i] = *(const f32x4*)&bufY[(ty+16*i)*128 + k0];
      const f32x4 avv = *(const f32x4*)&av[k0];
      #pragma unroll
      for (int i=0;i<8;i++) t1a[i] += a4[i]*a4[i]*avv;
      #pragma unroll
      for (int kk=0;kk<4;kk++){
        const f32x4 b0 = *(const f32x4*)&bufX[(k0+kk)*128 + 4*tx];
        const f32x4 b1 = *(const f32x4*)&bufX[(k0+kk)*128 + 4*tx + 64];
        #pragma unroll
        for (int i=0;i<8;i++){ g[i][0] += a4[i][kk]*b0; g[i][1] += a4[i][kk]*b1; }
      }
    }

    // ---- lk = -(0.5*C + 0.5*(t1 + t2 - 2G)) / eps  (in registers)
    f32x4 lk_[8][2];
    #pragma unroll
    for (int i=0;i<8;i++){
      const float t1v = t1a[i][0]+t1a[i][1]+t1a[i][2]+t1a[i][3];
      const float* Cr = Cb + (ty+16*i)*128;
      const f32x4 c0 = *(const f32x4*)(Cr + 4*tx);
      const f32x4 c1 = *(const f32x4*)(Cr + 4*tx + 64);
      lk_[i][0] = -inve*(0.5f*c0 + 0.5f*(t1v + t2p0 - 2.0f*g[i][0]));
      lk_[i][1] = -inve*(0.5f*c1 + 0.5f*(t1v + t2p1 - 2.0f*g[i][1]));
    }

    // ---- Sinkhorn, 10 iterations, in registers
    float lu[8];
    f32x4 lv0={0.f,0.f,0.f,0.f}, lv1={0.f,0.f,0.f,0.f};
    for (int it=0; it<10; it++){
      // u-pass: row-wise lse over cols (tx-shuffles)
      #pragma unroll
      for (int i=0;i<8;i++){
        const f32x4 v0 = lk_[i][0] + lv0, v1 = lk_[i][1] + lv1;
        float mx = fmaxf(fmaxf(fmaxf(v0[0],v0[1]),fmaxf(v0[2],v0[3])),
                         fmaxf(fmaxf(v1[0],v1[1]),fmaxf(v1[2],v1[3])));
        mx = fmaxf(mx,__shfl_xor(mx,1)); mx = fmaxf(mx,__shfl_xor(mx,2));
        mx = fmaxf(mx,__shfl_xor(mx,4)); mx = fmaxf(mx,__shfl_xor(mx,8));
        float s = __expf(v0[0]-mx)+__expf(v0[1]-mx)+__expf(v0[2]-mx)+__expf(v0[3]-mx)
                + __expf(v1[0]-mx)+__expf(v1[1]-mx)+__expf(v1[2]-mx)+__expf(v1[3]-mx);
        s += __shfl_xor(s,1); s += __shfl_xor(s,2); s += __shfl_xor(s,4); s += __shfl_xor(s,8);
        lu[i] = rho*(lmu_r[i] - (mx + __logf(s)));
      }
      // v-pass: col-wise lse over rows (ty-shuffles + cross-wave merge)
      #pragma unroll
      for (int j=0;j<2;j++){
        #pragma unroll
        for (int e=0;e<4;e++){
          float m0 = lk_[0][j][e]+lu[0];
          #pragma unroll
          for (int i=1;i<8;i++) m0 = fmaxf(m0, lk_[i][j][e]+lu[i]);
          m0 = fmaxf(m0,__shfl_xor(m0,16)); m0 = fmaxf(m0,__shfl_xor(m0,32));
          float s = 0.f;
          #pragma unroll
          for (int i=0;i<8;i++) s += __expf(lk_[i][j][e]+lu[i]-m0);
          s += __shfl_xor(s,16); s += __shfl_xor(s,32);
          if ((lane>>4)==0){ pb[wv][4*tx+64*j+e][0]=m0; pb[wv][4*tx+64*j+e][1]=s; }
        }
      }
      __syncthreads();
      if (tid<128){
        float MX = fmaxf(fmaxf(pb[0][tid][0],pb[1][tid][0]),
                         fmaxf(pb[2][tid][0],pb[3][tid][0]));
        float S = pb[0][tid][1]*__expf(pb[0][tid][0]-MX)
                + pb[1][tid][1]*__expf(pb[1][tid][0]-MX)
                + pb[2][tid][1]*__expf(pb[2][tid][0]-MX)
                + pb[3][tid][1]*__expf(pb[3][tid][0]-MX);
        lvs[tid] = rho*(lnus[tid] - (MX + __logf(S)));
      }
      __syncthreads();
      lv0 = *(const f32x4*)&lvs[4*tx];
      lv1 = *(const f32x4*)&lvs[64+4*tx];
    }

    // ---- T = exp(lu + lk + lv)
    #pragma unroll
    for (int i=0;i<8;i++){
      const f32x4 e0 = lk_[i][0] + lv0 + lu[i];
      const f32x4 e1 = lk_[i][1] + lv1 + lu[i];
      f32x4 t0, t1;
      #pragma unroll
      for (int e=0;e<4;e++){ t0[e]=__expf(e0[e]); t1[e]=__expf(e1[e]); }
      Tf[i][0]=t0; Tf[i][1]=t1;
    }

    if (outer==4){
      // cost = sum(T * C_fgw), C_fgw = -eps*lk ; store final T
      float cp = 0.f;
      float* Tb = T_out + (size_t)b*16384;
      #pragma unroll
      for (int i=0;i<8;i++){
        *(f32x4*)(Tb + (ty+16*i)*128 + 4*tx     ) = Tf[i][0];
        *(f32x4*)(Tb + (ty+16*i)*128 + 4*tx + 64) = Tf[i][1];
        const f32x4 p0 = Tf[i][0]*lk_[i][0], p1 = Tf[i][1]*lk_[i][1];
        cp += p0[0]+p0[1]+p0[2]+p0[3]+p1[0]+p1[1]+p1[2]+p1[3];
      }
      cp *= -eps;
      #pragma unroll
      for (int off=1;off<64;off<<=1) cp += __shfl_xor(cp, off);
      if (lane==0) red[wv] = cp;
      __syncthreads();
      if (tid==0){
        float tot = red[0]+red[1]+red[2]+red[3];
        cost_final = tot;
        cost_out[b] = tot;
        sim_out[b]  = 1.0f/(1.0f + __expf(tot));
      }
    }
  }
  (void)cost_final;
}

// ---------------------------------------------------------------------------
extern "C" void kernel_launch(void* const* d_in, const int* in_sizes, int n_in,
                              void* d_out, int out_size, void* d_ws, size_t ws_size,
                              hipStream_t stream){
  const float* sq      = (const float*)d_in[0];
  const float* sr      = (const float*)d_in[1];
  const float* mask_q  = (const float*)d_in[2];
  const float* mask_r  = (const float*)d_in[3];
  const float* cq      = (const float*)d_in[4];
  const float* cr      = (const float*)d_in[5];
  const float* W1      = (const float*)d_in[6];
  const float* b1      = (const float*)d_in[7];
  const float* W2      = (const float*)d_in[8];
  const float* b2      = (const float*)d_in[9];
  const float* log_eps = (const float*)d_in[10];

  float* out  = (float*)d_out;
  float* sim  = out;                 // [256]
  float* Tm   = out + 256;           // [256][128][128]
  float* Cm   = Tm + 4194304;        // [256][128][128]
  float* cost = Cm + 4194304;        // [256]

  char* ws = (char*)d_ws;
  size_t off = 0;
  auto alloc = [&](size_t bytes)->void*{ void* p = ws + off; off += (bytes+255)&~(size_t)255; return p; };
  u16*   SQB = (u16*)  alloc(33554432);   // sq bf16, later Pq
  u16*   SRB = (u16*)  alloc(33554432);   // sr bf16, later Pr (contiguous with SQB)
  u16*   HQ  = (u16*)  alloc(33554432);   // hidden q, later cq bf16
  u16*   HR  = (u16*)  alloc(33554432);   // hidden r, later cr bf16 (contiguous with HQ)
  u16*   W1T = (u16*)  alloc(524288);
  u16*   W2T = (u16*)  alloc(524288);
  float* NP  = (float*)alloc(262144);     // norms of P rows (65536)
  float* NCQ = (float*)alloc(131072);
  float* NCR = (float*)alloc(131072);
  float* LMU = (float*)alloc(131072);
  float* LNU = (float*)alloc(131072);
  float* MUA = (float*)alloc(131072);
  float* NUA = (float*)alloc(131072);
  float* SQM = (float*)alloc(16777216);   // Sq
  float* SRM = (float*)alloc(16777216);   // Sr
  (void)ws_size; (void)in_sizes; (void)n_in; (void)out_size;

  u16* PQ  = SQB;          // gemm2 output overwrites sq-bf16 region
  u16* CQB = HQ;           // centroid bf16 reuses hidden region (after gemm2)
  u16* CRB = HR;

  prepw_k<<<1024,256,0,stream>>>(W1, W1T);
  prepw_k<<<1024,256,0,stream>>>(W2, W2T);
  cvt_k<<<8192,256,0,stream>>>(sq, SQB, nullptr, 32768);
  cvt_k<<<8192,256,0,stream>>>(sr, SRB, nullptr, 32768);
  gemm_k<1><<<2048,256,0,stream>>>(SQB, W1T, b1, HQ);   // H = relu(X@W1+b1)
  gemm_k<0><<<2048,256,0,stream>>>(HQ, W2T, b2, PQ);    // P = H@W2+b2
  normb_k<<<16384,256,0,stream>>>(PQ, NP, 65536);
  cvt_k<<<8192,256,0,stream>>>(cq, CQB, NCQ, 32768);
  cvt_k<<<8192,256,0,stream>>>(cr, CRB, NCR, 32768);
  pdist_k<<<256,256,0,stream>>>(PQ, PQ + (size_t)32768*512, NP, NP + 32768, Cm);
  pdist_k<<<256,256,0,stream>>>(CQB, CQB, NCQ, NCQ, SQM);
  pdist_k<<<256,256,0,stream>>>(CRB, CRB, NCR, NCR, SRM);
  prep_k<<<256,128,0,stream>>>(mask_q, mask_r, LMU, LNU, MUA, NUA);
  fgw_loop_k<<<256,256,0,stream>>>(SQM, SRM, Cm, MUA, NUA, LMU, LNU, log_eps,
                                   Tm, cost, sim);
}

// Round 3
// 500.357 us; speedup vs baseline: 1.4133x; 1.4133x over previous
//
#include <hip/hip_runtime.h>
#include <math.h>

typedef unsigned short u16;
typedef __attribute__((ext_vector_type(4))) float f32x4;
typedef __attribute__((ext_vector_type(8))) short bf16x8;
typedef __attribute__((ext_vector_type(4))) unsigned short u16x4;
typedef __attribute__((ext_vector_type(8))) unsigned short u16x8;

#define DEVI static __device__ __forceinline__

DEVI float b2f(u16 u){ union{float f; unsigned i;} v; v.i = ((unsigned)u)<<16; return v.f; }
DEVI u16 f2b(float f){ union{float f; unsigned i;} v; v.f=f;
  unsigned r = v.i + 0x7fffu + ((v.i>>16)&1u); return (u16)(r>>16); }

DEVI void gload_lds16(const void* g, void* l){
  __builtin_amdgcn_global_load_lds((const __attribute__((address_space(1))) void*)g,
                                   (__attribute__((address_space(3))) void*)l, 16, 0, 0);
}

// ---------------------------------------------------------------------------
// W (512x512 f32, row-major [k][c]) -> Wt bf16 [c][k]
__global__ void prepw_k(const float* __restrict__ W, u16* __restrict__ Wt){
  int id = blockIdx.x*256 + threadIdx.x;
  int k = id>>9, c = id&511;
  Wt[c*512 + k] = f2b(W[id]);
}

// f32 [nrows][512] -> bf16 [nrows][512] (+ optional row norms of the bf16 values)
__global__ void cvt_k(const float* __restrict__ src, u16* __restrict__ dst,
                      float* __restrict__ norms, int nrows){
  int gw = (int)((blockIdx.x*blockDim.x + threadIdx.x)>>6);
  int lane = threadIdx.x & 63;
  if (gw >= nrows) return;
  const float* s = src + (size_t)gw*512;
  u16* d = dst + (size_t)gw*512;
  float acc = 0.f;
  #pragma unroll
  for (int q=0;q<2;q++){
    f32x4 v = *(const f32x4*)(s + q*256 + lane*4);
    u16x4 u;
    #pragma unroll
    for (int e=0;e<4;e++){
      u16 b = f2b(v[e]); u[e] = b;
      float fv = b2f(b); acc += fv*fv;
    }
    *(u16x4*)(d + q*256 + lane*4) = u;
  }
  #pragma unroll
  for (int off=1;off<64;off<<=1) acc += __shfl_xor(acc, off);
  if (norms != nullptr && lane==0) norms[gw] = acc;
}

// row norms of a bf16 [nrows][512] matrix
__global__ void normb_k(const u16* __restrict__ src, float* __restrict__ norms, int nrows){
  int gw = (int)((blockIdx.x*blockDim.x + threadIdx.x)>>6);
  int lane = threadIdx.x & 63;
  if (gw >= nrows) return;
  const u16* s = src + (size_t)gw*512;
  u16x8 v = *(const u16x8*)(s + lane*8);
  float acc = 0.f;
  #pragma unroll
  for (int e=0;e<8;e++){ float f = b2f(v[e]); acc += f*f; }
  #pragma unroll
  for (int off=1;off<64;off<<=1) acc += __shfl_xor(acc, off);
  if (lane==0) norms[gw] = acc;
}

// ---------------------------------------------------------------------------
// OUT[r][c] = act(sum_k X[r][k]*W[k][c] + bias[c]) ; X bf16 [R][512], Wt bf16 [c][k]
template<int ACT>
__global__ __launch_bounds__(256) void gemm_k(const u16* __restrict__ X,
    const u16* __restrict__ Wt, const float* __restrict__ bias, u16* __restrict__ OUT){
  __shared__ __align__(16) u16 sA[128*64];
  __shared__ __align__(16) u16 sB[128*64];
  const int tid = threadIdx.x, wave = tid>>6, lane = tid&63;
  const int bid = (blockIdx.x&7)*256 + (blockIdx.x>>3);
  const int rblk = bid>>2, cb = (bid&3)<<7;
  const u16* Xb = X + (size_t)rblk*(128*512);
  const u16* Wb = Wt + (size_t)cb*512;
  const int lrow = lane&15, lg = lane>>4, wr = wave>>1, wc = wave&1;
  f32x4 acc[4][4] = {};
  for (int s=0;s<8;s++){
    const int k0 = s<<6;
    #pragma unroll
    for (int q=0;q<4;q++){
      const int i = (wave<<2)+q;
      const int row = (i<<3) + (lane>>3);
      const int cd = (lane&7) ^ (row&7);
      gload_lds16(Xb + row*512 + k0 + (cd<<3), sA + i*512);
      gload_lds16(Wb + row*512 + k0 + (cd<<3), sB + i*512);
    }
    __syncthreads();
    #pragma unroll
    for (int kh=0;kh<2;kh++){
      bf16x8 a_[4], b_[4];
      #pragma unroll
      for (int i=0;i<4;i++){
        const int ra = (wr<<6)+(i<<4)+lrow;
        a_[i] = *(const bf16x8*)(sA + ra*64 + ((((kh<<2)+lg)^(ra&7))<<3));
        const int rb = (wc<<6)+(i<<4)+lrow;
        b_[i] = *(const bf16x8*)(sB + rb*64 + ((((kh<<2)+lg)^(rb&7))<<3));
      }
      #pragma unroll
      for (int i=0;i<4;i++)
        #pragma unroll
        for (int j=0;j<4;j++)
          acc[i][j] = __builtin_amdgcn_mfma_f32_16x16x32_bf16(a_[i], b_[j], acc[i][j], 0,0,0);
    }
    __syncthreads();
  }
  #pragma unroll
  for (int j=0;j<4;j++){
    const int col = cb + (wc<<6) + (j<<4) + lrow;
    const float bv = bias[col];
    #pragma unroll
    for (int i=0;i<4;i++){
      const int row0 = (rblk<<7) + (wr<<6) + (i<<4) + (lg<<2);
      #pragma unroll
      for (int r=0;r<4;r++){
        float v = acc[i][j][r] + bv;
        if (ACT) v = fmaxf(v, 0.f);
        OUT[(size_t)(row0+r)*512 + col] = f2b(v);
      }
    }
  }
}

// pdist: MODE 0 -> OUT f32 [b][k][m]. MODE 1 -> S2t f32 plane (S^2, transposed =
// same by symmetry) + SHL: hi/lo bf16 planes, transposed + XOR-granule-swizzled
// (plane[c][r] = S[r][c]; granule g' = (r/8) ^ (c&15) within each 256B row).
template<int MODE>
__global__ __launch_bounds__(256) void pdist_k(const u16* __restrict__ Xa,
    const u16* __restrict__ Xb2, const float* __restrict__ na, const float* __restrict__ nb,
    float* __restrict__ OUT, float* __restrict__ S2t, char* __restrict__ SHL){
  __shared__ __align__(16) u16 sA[128*64];
  __shared__ __align__(16) u16 sB[128*64];
  const int tid = threadIdx.x, wave = tid>>6, lane = tid&63;
  const int b = blockIdx.x;
  const u16* Ab = Xa + (size_t)b*(128*512);
  const u16* Bb = Xb2 + (size_t)b*(128*512);
  const int lrow = lane&15, lg = lane>>4, wr = wave>>1, wc = wave&1;
  f32x4 acc[4][4] = {};
  for (int s=0;s<8;s++){
    const int k0 = s<<6;
    #pragma unroll
    for (int q=0;q<4;q++){
      const int i = (wave<<2)+q;
      const int row = (i<<3) + (lane>>3);
      const int cd = (lane&7) ^ (row&7);
      gload_lds16(Ab + row*512 + k0 + (cd<<3), sA + i*512);
      gload_lds16(Bb + row*512 + k0 + (cd<<3), sB + i*512);
    }
    __syncthreads();
    #pragma unroll
    for (int kh=0;kh<2;kh++){
      bf16x8 a_[4], b_[4];
      #pragma unroll
      for (int i=0;i<4;i++){
        const int ra = (wr<<6)+(i<<4)+lrow;
        a_[i] = *(const bf16x8*)(sA + ra*64 + ((((kh<<2)+lg)^(ra&7))<<3));
        const int rb = (wc<<6)+(i<<4)+lrow;
        b_[i] = *(const bf16x8*)(sB + rb*64 + ((((kh<<2)+lg)^(rb&7))<<3));
      }
      #pragma unroll
      for (int i=0;i<4;i++)
        #pragma unroll
        for (int j=0;j<4;j++)
          acc[i][j] = __builtin_amdgcn_mfma_f32_16x16x32_bf16(a_[i], b_[j], acc[i][j], 0,0,0);
    }
    __syncthreads();
  }
  #pragma unroll
  for (int j=0;j<4;j++){
    const int col = (wc<<6)+(j<<4)+lrow;
    const float nbv = nb[b*128+col];
    #pragma unroll
    for (int i=0;i<4;i++){
      const int row0 = (wr<<6)+(i<<4)+(lg<<2);
      float sv[4];
      #pragma unroll
      for (int r=0;r<4;r++){
        float n2 = na[b*128+row0+r] + nbv - 2.0f*acc[i][j][r];
        sv[r] = sqrtf(fmaxf(n2, 1e-6f));
      }
      if (MODE==0){
        #pragma unroll
        for (int r=0;r<4;r++)
          OUT[(size_t)b*16384 + (size_t)(row0+r)*128 + col] = sv[r];
      } else {
        u16x4 hi4, lo4; f32x4 s2q;
        #pragma unroll
        for (int r=0;r<4;r++){
          u16 h = f2b(sv[r]); hi4[r] = h;
          lo4[r] = f2b(sv[r] - b2f(h));
          s2q[r] = sv[r]*sv[r];
        }
        const int sa = col*256 + ((((row0>>3)^col)&15)<<4) + ((row0&7)<<1);
        char* base = SHL + (size_t)b*65536;
        *(u16x4*)(base + sa) = hi4;
        *(u16x4*)(base + 32768 + sa) = lo4;
        *(f32x4*)(S2t + (size_t)b*16384 + col*128 + row0) = s2q;
      }
    }
  }
}

// ---------------------------------------------------------------------------
// mu/nu + their logs. 256 blocks x 128 threads.
__global__ void prep_k(const float* __restrict__ mask_q, const float* __restrict__ mask_r,
                       float* __restrict__ lmu, float* __restrict__ lnu,
                       float* __restrict__ mu, float* __restrict__ nu){
  int b = blockIdx.x, t = threadIdx.x;
  __shared__ float red[4];
  float mq = mask_q[b*128+t], mr = mask_r[b*128+t];
  float s1 = mq, s2 = mr;
  #pragma unroll
  for (int off=1;off<64;off<<=1){ s1 += __shfl_xor(s1,off); s2 += __shfl_xor(s2,off); }
  if ((t&63)==0){ red[t>>6] = s1; red[2+(t>>6)] = s2; }
  __syncthreads();
  float sumq = red[0]+red[1], sumr = red[2]+red[3];
  float muv = mq/(sumq+1e-8f), nuv = mr/(sumr+1e-8f);
  lmu[b*128+t] = __logf(fmaxf(muv,1e-8f));
  lnu[b*128+t] = __logf(fmaxf(nuv,1e-8f));
  mu[b*128+t] = muv;
  nu[b*128+t] = nuv;
}

// ---------------------------------------------------------------------------
// Entire 5-iter FGW loop, one 512-thread block per batch. Matmuls via
// split-bf16 MFMA (hi*hi + hi*lo + lo*hi); T and lk live in G^T fragment
// layout registers: element (k = 16*kt + (lane&15), n = 16*w + 4*(lane>>4) + reg).
__global__ __launch_bounds__(512,1) void fgw_loop_k(
    const char* __restrict__ SQHL, const char* __restrict__ SRHL,
    const float* __restrict__ SQ2, const float* __restrict__ SR2,
    const float* __restrict__ C_g,
    const float* __restrict__ MU, const float* __restrict__ NU,
    const float* __restrict__ LMU, const float* __restrict__ LNU,
    const float* __restrict__ log_eps,
    float* __restrict__ T_out, float* __restrict__ cost_out, float* __restrict__ sim_out)
{
  __shared__ __align__(16) char bufT[65536];   // hi plane [0,32K), lo plane [32K,64K)
  __shared__ __align__(16) char bufS[65536];   // staged Sr then Sq (hi/lo planes)
  __shared__ float pbm[8][128], pbs[8][128];
  __shared__ float avs[128], bvs[128], t1s[128], t2s[128], lus[128];
  __shared__ float mus_[128], nus_[128], lmus_[128], lnus_[128];
  __shared__ float redc[8];

  const int b = blockIdx.x, tid = threadIdx.x;
  const int w = tid>>6, lane = tid&63, l15 = lane&15, lg = lane>>4;
  const char* SqHLb = SQHL + (size_t)b*65536;
  const char* SrHLb = SRHL + (size_t)b*65536;
  const float* Sq2b = SQ2 + (size_t)b*16384;
  const float* Sr2b = SR2 + (size_t)b*16384;
  const float* Cb   = C_g + (size_t)b*16384;

  float eps = __expf(log_eps[0]); eps = fminf(fmaxf(eps,0.01f),0.5f);
  const float rho = 0.1f/(0.1f+eps), inve = 1.0f/eps;

  if (tid<128){ mus_[tid]=MU[b*128+tid]; nus_[tid]=NU[b*128+tid];
                lmus_[tid]=LMU[b*128+tid]; lnus_[tid]=LNU[b*128+tid]; }
  __syncthreads();

  const int n0 = 16*w + 4*lg;                  // base n of this thread's 4 regs
  const f32x4 nu4  = *(const f32x4*)&nus_[n0];
  const f32x4 lnu4 = *(const f32x4*)&lnus_[n0];

  // address precompute (XOR-granule swizzle within 256B plane rows)
  const int rowA256 = (16*w + l15)*256;        // A-frag row base (both phases)
  const int glo2 = lg ^ (l15 & 3);
  const int ghi2 = l15 & 12;
  const int wtail = l15*256 + ((((2*w + (lg>>1)) ^ l15)&15)<<4) + ((lg&1)<<3);

  // T0 = mu (x) nu
  f32x4 Tf[8];
  #pragma unroll
  for (int kt=0;kt<8;kt++) Tf[kt] = mus_[16*kt+l15]*nu4;

  f32x4 lk_[8];
  float lu[8];

  for (int outer=0; outer<5; outer++){
    // 1) stage Sr hi/lo planes -> bufS (linear; global is pre-swizzled)
    #pragma unroll
    for (int r2=0;r2<8;r2++)
      gload_lds16(SrHLb + r2*8192 + tid*16, bufS + r2*8192 + tid*16);
    // 2) write T hi/lo planes -> bufT (plane[k][m], swizzled)
    #pragma unroll
    for (int kt=0;kt<8;kt++){
      u16x4 hi4, lo4;
      #pragma unroll
      for (int r=0;r<4;r++){
        u16 h = f2b(Tf[kt][r]); hi4[r] = h;
        lo4[r] = f2b(Tf[kt][r] - b2f(h));
      }
      const int sa = kt*4096 + wtail;
      *(u16x4*)(bufT + sa) = hi4;
      *(u16x4*)(bufT + 32768 + sa) = lo4;
    }
    // 3) av partials (sum over n), bv complete (sum over k)
    #pragma unroll
    for (int kt=0;kt<8;kt++){
      f32x4 v = Tf[kt];
      float s = v[0]+v[1]+v[2]+v[3];
      s += __shfl_xor(s,16); s += __shfl_xor(s,32);
      if (lg==0) pbm[w][16*kt+l15] = s;
    }
    {
      f32x4 p = Tf[0];
      #pragma unroll
      for (int kt=1;kt<8;kt++) p += Tf[kt];
      #pragma unroll
      for (int e=0;e<4;e++){
        float v = p[e];
        v += __shfl_xor(v,1); v += __shfl_xor(v,2);
        v += __shfl_xor(v,4); v += __shfl_xor(v,8);
        if (l15==0) bvs[n0+e] = v;
      }
    }
    __syncthreads();                           // Sr staged, T planes, pbm, bvs
    if (tid<128){
      float s = pbm[0][tid];
      #pragma unroll
      for (int w2=1;w2<8;w2++) s += pbm[w2][tid];
      avs[tid] = s;
    }
    __syncthreads();                           // avs ready
    // 4) t1 = Sq^2 @ av, t2 = Sr^2 @ bv (symmetric planes, row access)
    {
      const int k = tid>>2, q = tid&3;
      const float* r1 = Sq2b + k*128 + q*32;
      const float* r2p = Sr2b + k*128 + q*32;
      f32x4 a1 = {0.f,0.f,0.f,0.f}, a2 = {0.f,0.f,0.f,0.f};
      #pragma unroll
      for (int i=0;i<8;i++){
        a1 += (*(const f32x4*)(r1+4*i)) * (*(const f32x4*)(avs+q*32+4*i));
        a2 += (*(const f32x4*)(r2p+4*i)) * (*(const f32x4*)(bvs+q*32+4*i));
      }
      float s1 = a1[0]+a1[1]+a1[2]+a1[3];
      float s2 = a2[0]+a2[1]+a2[2]+a2[3];
      s1 += __shfl_xor(s1,1); s1 += __shfl_xor(s1,2);
      s2 += __shfl_xor(s2,1); s2 += __shfl_xor(s2,2);
      if (q==0){ t1s[k]=s1; t2s[k]=s2; }
    }
    // 5) phase A: TSr = T @ Sr (wave w -> rows 16w..16w+15, all 8 col tiles)
    f32x4 acc1[8] = {};
    #pragma unroll
    for (int qt=0;qt<4;qt++){
      const int colOff = (((4*qt) ^ ghi2) | glo2) << 4;
      const bf16x8 ahi = *(const bf16x8*)(bufT + rowA256 + colOff);
      const bf16x8 alo = *(const bf16x8*)(bufT + 32768 + rowA256 + colOff);
      const int bbase = l15*256 + colOff;
      #pragma unroll
      for (int nt=0;nt<8;nt++){
        const bf16x8 bhi = *(const bf16x8*)(bufS + nt*4096 + bbase);
        const bf16x8 blo = *(const bf16x8*)(bufS + 32768 + nt*4096 + bbase);
        acc1[nt] = __builtin_amdgcn_mfma_f32_16x16x32_bf16(ahi, bhi, acc1[nt], 0,0,0);
        acc1[nt] = __builtin_amdgcn_mfma_f32_16x16x32_bf16(ahi, blo, acc1[nt], 0,0,0);
        acc1[nt] = __builtin_amdgcn_mfma_f32_16x16x32_bf16(alo, bhi, acc1[nt], 0,0,0);
      }
    }
    __syncthreads();                           // phase A LDS reads complete
    // 6) stage Sq; write TSr^T hi/lo planes into bufT
    #pragma unroll
    for (int r2=0;r2<8;r2++)
      gload_lds16(SqHLb + r2*8192 + tid*16, bufS + r2*8192 + tid*16);
    #pragma unroll
    for (int nt=0;nt<8;nt++){
      u16x4 hi4, lo4;
      #pragma unroll
      for (int r=0;r<4;r++){
        u16 h = f2b(acc1[nt][r]); hi4[r] = h;
        lo4[r] = f2b(acc1[nt][r] - b2f(h));
      }
      const int sa = nt*4096 + wtail;          // plane[n][l], transposed write
      *(u16x4*)(bufT + sa) = hi4;
      *(u16x4*)(bufT + 32768 + sa) = lo4;
    }
    __syncthreads();                           // Sq staged + TSRt planes ready
    // 7) phase B: G^T = TSr^T @ Sq (wave w -> n rows 16w.., 8 k col tiles)
    f32x4 acc2[8] = {};
    #pragma unroll
    for (int qt=0;qt<4;qt++){
      const int colOff = (((4*qt) ^ ghi2) | glo2) << 4;
      const bf16x8 ahi = *(const bf16x8*)(bufT + rowA256 + colOff);
      const bf16x8 alo = *(const bf16x8*)(bufT + 32768 + rowA256 + colOff);
      const int bbase = l15*256 + colOff;
      #pragma unroll
      for (int kt=0;kt<8;kt++){
        const bf16x8 bhi = *(const bf16x8*)(bufS + kt*4096 + bbase);
        const bf16x8 blo = *(const bf16x8*)(bufS + 32768 + kt*4096 + bbase);
        acc2[kt] = __builtin_amdgcn_mfma_f32_16x16x32_bf16(ahi, bhi, acc2[kt], 0,0,0);
        acc2[kt] = __builtin_amdgcn_mfma_f32_16x16x32_bf16(ahi, blo, acc2[kt], 0,0,0);
        acc2[kt] = __builtin_amdgcn_mfma_f32_16x16x32_bf16(alo, bhi, acc2[kt], 0,0,0);
      }
    }
    // 8) lk = -(0.5C + 0.5(t1 + t2 - 2G))/eps
    const f32x4 t24 = *(const f32x4*)&t2s[n0];
    #pragma unroll
    for (int kt=0;kt<8;kt++){
      const int k = 16*kt + l15;
      const f32x4 c4 = *(const f32x4*)(Cb + k*128 + n0);
      const float t1v = t1s[k];
      lk_[kt] = -inve*(0.5f*c4 + 0.5f*(t1v + t24 - 2.0f*acc2[kt]));
    }
    // 9) Sinkhorn: 10 iterations
    f32x4 lv4 = {0.f,0.f,0.f,0.f};
    for (int it=0; it<10; it++){
      // u-pass: lse over n for each k
      #pragma unroll
      for (int kt=0;kt<8;kt++){
        const f32x4 t = lk_[kt] + lv4;
        float mx = fmaxf(fmaxf(t[0],t[1]), fmaxf(t[2],t[3]));
        mx = fmaxf(mx, __shfl_xor(mx,16));
        mx = fmaxf(mx, __shfl_xor(mx,32));
        float s = __expf(t[0]-mx)+__expf(t[1]-mx)+__expf(t[2]-mx)+__expf(t[3]-mx);
        s += __shfl_xor(s,16); s += __shfl_xor(s,32);
        if (lg==0){ pbm[w][16*kt+l15] = mx; pbs[w][16*kt+l15] = s; }
      }
      __syncthreads();
      if (tid<128){
        float MX = pbm[0][tid];
        #pragma unroll
        for (int w2=1;w2<8;w2++) MX = fmaxf(MX, pbm[w2][tid]);
        float S = 0.f;
        #pragma unroll
        for (int w2=0;w2<8;w2++) S += pbs[w2][tid]*__expf(pbm[w2][tid]-MX);
        lus[tid] = rho*(lmus_[tid] - (MX + __logf(S)));
      }
      __syncthreads();
      #pragma unroll
      for (int kt=0;kt<8;kt++) lu[kt] = lus[16*kt+l15];
      // v-pass: lse over k for each n (fully in-wave)
      f32x4 vm = lk_[0] + lu[0];
      #pragma unroll
      for (int kt=1;kt<8;kt++){
        const f32x4 t = lk_[kt] + lu[kt];
        vm[0]=fmaxf(vm[0],t[0]); vm[1]=fmaxf(vm[1],t[1]);
        vm[2]=fmaxf(vm[2],t[2]); vm[3]=fmaxf(vm[3],t[3]);
      }
      #pragma unroll
      for (int d=1; d<16; d<<=1){
        vm[0]=fmaxf(vm[0],__shfl_xor(vm[0],d));
        vm[1]=fmaxf(vm[1],__shfl_xor(vm[1],d));
        vm[2]=fmaxf(vm[2],__shfl_xor(vm[2],d));
        vm[3]=fmaxf(vm[3],__shfl_xor(vm[3],d));
      }
      f32x4 vs = {0.f,0.f,0.f,0.f};
      #pragma unroll
      for (int kt=0;kt<8;kt++){
        const f32x4 t = lk_[kt] + lu[kt] - vm;
        vs[0]+=__expf(t[0]); vs[1]+=__expf(t[1]);
        vs[2]+=__expf(t[2]); vs[3]+=__expf(t[3]);
      }
      #pragma unroll
      for (int d=1; d<16; d<<=1){
        vs[0]+=__shfl_xor(vs[0],d); vs[1]+=__shfl_xor(vs[1],d);
        vs[2]+=__shfl_xor(vs[2],d); vs[3]+=__shfl_xor(vs[3],d);
      }
      f32x4 lse;
      lse[0]=vm[0]+__logf(vs[0]); lse[1]=vm[1]+__logf(vs[1]);
      lse[2]=vm[2]+__logf(vs[2]); lse[3]=vm[3]+__logf(vs[3]);
      lv4 = rho*(lnu4 - lse);
    }
    // 10) T = exp(lu + lk + lv)
    #pragma unroll
    for (int kt=0;kt<8;kt++){
      const f32x4 e4 = lk_[kt] + lv4 + lu[kt];
      f32x4 t;
      t[0]=__expf(e4[0]); t[1]=__expf(e4[1]); t[2]=__expf(e4[2]); t[3]=__expf(e4[3]);
      Tf[kt] = t;
    }
    if (outer==4){
      float cp = 0.f;
      float* Tb = T_out + (size_t)b*16384;
      #pragma unroll
      for (int kt=0;kt<8;kt++){
        const int k = 16*kt + l15;
        *(f32x4*)(Tb + k*128 + n0) = Tf[kt];
        const f32x4 p = Tf[kt]*lk_[kt];
        cp += p[0]+p[1]+p[2]+p[3];
      }
      cp *= -eps;
      #pragma unroll
      for (int off=1;off<64;off<<=1) cp += __shfl_xor(cp, off);
      if (lane==0) redc[w] = cp;
      __syncthreads();
      if (tid==0){
        float tot = 0.f;
        #pragma unroll
        for (int w2=0;w2<8;w2++) tot += redc[w2];
        cost_out[b] = tot;
        sim_out[b]  = 1.0f/(1.0f + __expf(tot));
      }
    }
  }
}

// ---------------------------------------------------------------------------
extern "C" void kernel_launch(void* const* d_in, const int* in_sizes, int n_in,
                              void* d_out, int out_size, void* d_ws, size_t ws_size,
                              hipStream_t stream){
  const float* sq      = (const float*)d_in[0];
  const float* sr      = (const float*)d_in[1];
  const float* mask_q  = (const float*)d_in[2];
  const float* mask_r  = (const float*)d_in[3];
  const float* cq      = (const float*)d_in[4];
  const float* cr      = (const float*)d_in[5];
  const float* W1      = (const float*)d_in[6];
  const float* b1      = (const float*)d_in[7];
  const float* W2      = (const float*)d_in[8];
  const float* b2      = (const float*)d_in[9];
  const float* log_eps = (const float*)d_in[10];

  float* out  = (float*)d_out;
  float* sim  = out;                 // [256]
  float* Tm   = out + 256;           // [256][128][128]
  float* Cm   = Tm + 4194304;        // [256][128][128]
  float* cost = Cm + 4194304;        // [256]

  char* ws = (char*)d_ws;
  size_t off = 0;
  auto alloc = [&](size_t bytes)->void*{ void* p = ws + off; off += (bytes+255)&~(size_t)255; return p; };
  u16*   SQB = (u16*)  alloc(33554432);   // sq bf16 -> Pq rows 0..32767 -> plane region
  u16*   SRB = (u16*)  alloc(33554432);   // sr bf16 -> Pq rows 32768..65535 -> plane region
  u16*   HQ  = (u16*)  alloc(33554432);   // hidden q -> cq bf16
  u16*   HR  = (u16*)  alloc(33554432);   // hidden r -> cr bf16
  u16*   W1T = (u16*)  alloc(524288);
  u16*   W2T = (u16*)  alloc(524288);
  float* NP  = (float*)alloc(262144);     // norms of P rows (65536)
  float* NCQ = (float*)alloc(131072);
  float* NCR = (float*)alloc(131072);
  float* LMU = (float*)alloc(131072);
  float* LNU = (float*)alloc(131072);
  float* MUA = (float*)alloc(131072);
  float* NUA = (float*)alloc(131072);
  (void)ws_size; (void)in_sizes; (void)n_in; (void)out_size;

  u16* PQ  = SQB;          // gemm2 output (65536 rows, spans SQB+SRB)
  u16* CQB = HQ;
  u16* CRB = HR;

  // After pdist#1 consumes PQ, its 64MB region is reused for the loop planes:
  float* SQ2  = (float*)((char*)SQB);                 // 16MB f32  Sq^2
  float* SR2  = (float*)((char*)SQB + 16777216);      // 16MB f32  Sr^2
  char*  SQHL = (char*)SQB + 33554432;                // 16MB bf16 hi/lo Sq planes
  char*  SRHL = (char*)SQB + 50331648;                // 16MB bf16 hi/lo Sr planes

  prepw_k<<<1024,256,0,stream>>>(W1, W1T);
  prepw_k<<<1024,256,0,stream>>>(W2, W2T);
  cvt_k<<<8192,256,0,stream>>>(sq, SQB, nullptr, 32768);
  cvt_k<<<8192,256,0,stream>>>(sr, SRB, nullptr, 32768);
  gemm_k<1><<<2048,256,0,stream>>>(SQB, W1T, b1, HQ);   // H = relu(X@W1+b1)
  gemm_k<0><<<2048,256,0,stream>>>(HQ, W2T, b2, PQ);    // P = H@W2+b2
  normb_k<<<16384,256,0,stream>>>(PQ, NP, 65536);
  cvt_k<<<8192,256,0,stream>>>(cq, CQB, NCQ, 32768);
  cvt_k<<<8192,256,0,stream>>>(cr, CRB, NCR, 32768);
  pdist_k<0><<<256,256,0,stream>>>(PQ, PQ + (size_t)32768*512, NP, NP + 32768,
                                   Cm, nullptr, nullptr);
  pdist_k<1><<<256,256,0,stream>>>(CQB, CQB, NCQ, NCQ, nullptr, SQ2, SQHL);
  pdist_k<1><<<256,256,0,stream>>>(CRB, CRB, NCR, NCR, nullptr, SR2, SRHL);
  prep_k<<<256,128,0,stream>>>(mask_q, mask_r, LMU, LNU, MUA, NUA);
  fgw_loop_k<<<256,512,0,stream>>>(SQHL, SRHL, SQ2, SR2, Cm, MUA, NUA, LMU, LNU,
                                   log_eps, Tm, cost, sim);
}

// Round 4
// 477.393 us; speedup vs baseline: 1.4812x; 1.0481x over previous
//
#include <hip/hip_runtime.h>
#include <math.h>

typedef unsigned short u16;
typedef __attribute__((ext_vector_type(4))) float f32x4;
typedef __attribute__((ext_vector_type(8))) short bf16x8;
typedef __attribute__((ext_vector_type(4))) unsigned short u16x4;
typedef __attribute__((ext_vector_type(8))) unsigned short u16x8;

#define DEVI static __device__ __forceinline__

DEVI float b2f(u16 u){ union{float f; unsigned i;} v; v.i = ((unsigned)u)<<16; return v.f; }
DEVI u16 f2b(float f){ union{float f; unsigned i;} v; v.f=f;
  unsigned r = v.i + 0x7fffu + ((v.i>>16)&1u); return (u16)(r>>16); }

DEVI void gload_lds16(const void* g, void* l){
  __builtin_amdgcn_global_load_lds((const __attribute__((address_space(1))) void*)g,
                                   (__attribute__((address_space(3))) void*)l, 16, 0, 0);
}

DEVI f32x4 vmax4(f32x4 a, f32x4 b){
  f32x4 r; r[0]=fmaxf(a[0],b[0]); r[1]=fmaxf(a[1],b[1]);
  r[2]=fmaxf(a[2],b[2]); r[3]=fmaxf(a[3],b[3]); return r;
}

// ---------------------------------------------------------------------------
// W (512x512 f32, row-major [k][c]) -> Wt bf16 [c][k]
__global__ void prepw_k(const float* __restrict__ W, u16* __restrict__ Wt){
  int id = blockIdx.x*256 + threadIdx.x;
  int k = id>>9, c = id&511;
  Wt[c*512 + k] = f2b(W[id]);
}

// f32 [nrows][512] -> bf16 [nrows][512] (+ optional row norms of the bf16 values)
__global__ void cvt_k(const float* __restrict__ src, u16* __restrict__ dst,
                      float* __restrict__ norms, int nrows){
  int gw = (int)((blockIdx.x*blockDim.x + threadIdx.x)>>6);
  int lane = threadIdx.x & 63;
  if (gw >= nrows) return;
  const float* s = src + (size_t)gw*512;
  u16* d = dst + (size_t)gw*512;
  float acc = 0.f;
  #pragma unroll
  for (int q=0;q<2;q++){
    f32x4 v = *(const f32x4*)(s + q*256 + lane*4);
    u16x4 u;
    #pragma unroll
    for (int e=0;e<4;e++){
      u16 b = f2b(v[e]); u[e] = b;
      float fv = b2f(b); acc += fv*fv;
    }
    *(u16x4*)(d + q*256 + lane*4) = u;
  }
  #pragma unroll
  for (int off=1;off<64;off<<=1) acc += __shfl_xor(acc, off);
  if (norms != nullptr && lane==0) norms[gw] = acc;
}

// row norms of a bf16 [nrows][512] matrix
__global__ void normb_k(const u16* __restrict__ src, float* __restrict__ norms, int nrows){
  int gw = (int)((blockIdx.x*blockDim.x + threadIdx.x)>>6);
  int lane = threadIdx.x & 63;
  if (gw >= nrows) return;
  const u16* s = src + (size_t)gw*512;
  u16x8 v = *(const u16x8*)(s + lane*8);
  float acc = 0.f;
  #pragma unroll
  for (int e=0;e<8;e++){ float f = b2f(v[e]); acc += f*f; }
  #pragma unroll
  for (int off=1;off<64;off<<=1) acc += __shfl_xor(acc, off);
  if (lane==0) norms[gw] = acc;
}

// ---------------------------------------------------------------------------
// OUT[r][c] = act(sum_k X[r][k]*W[k][c] + bias[c]) ; X bf16 [R][512], Wt bf16 [c][k]
template<int ACT>
__global__ __launch_bounds__(256) void gemm_k(const u16* __restrict__ X,
    const u16* __restrict__ Wt, const float* __restrict__ bias, u16* __restrict__ OUT){
  __shared__ __align__(16) u16 sA[128*64];
  __shared__ __align__(16) u16 sB[128*64];
  const int tid = threadIdx.x, wave = tid>>6, lane = tid&63;
  const int bid = (blockIdx.x&7)*256 + (blockIdx.x>>3);
  const int rblk = bid>>2, cb = (bid&3)<<7;
  const u16* Xb = X + (size_t)rblk*(128*512);
  const u16* Wb = Wt + (size_t)cb*512;
  const int lrow = lane&15, lg = lane>>4, wr = wave>>1, wc = wave&1;
  f32x4 acc[4][4] = {};
  for (int s=0;s<8;s++){
    const int k0 = s<<6;
    #pragma unroll
    for (int q=0;q<4;q++){
      const int i = (wave<<2)+q;
      const int row = (i<<3) + (lane>>3);
      const int cd = (lane&7) ^ (row&7);
      gload_lds16(Xb + row*512 + k0 + (cd<<3), sA + i*512);
      gload_lds16(Wb + row*512 + k0 + (cd<<3), sB + i*512);
    }
    __syncthreads();
    #pragma unroll
    for (int kh=0;kh<2;kh++){
      bf16x8 a_[4], b_[4];
      #pragma unroll
      for (int i=0;i<4;i++){
        const int ra = (wr<<6)+(i<<4)+lrow;
        a_[i] = *(const bf16x8*)(sA + ra*64 + ((((kh<<2)+lg)^(ra&7))<<3));
        const int rb = (wc<<6)+(i<<4)+lrow;
        b_[i] = *(const bf16x8*)(sB + rb*64 + ((((kh<<2)+lg)^(rb&7))<<3));
      }
      #pragma unroll
      for (int i=0;i<4;i++)
        #pragma unroll
        for (int j=0;j<4;j++)
          acc[i][j] = __builtin_amdgcn_mfma_f32_16x16x32_bf16(a_[i], b_[j], acc[i][j], 0,0,0);
    }
    __syncthreads();
  }
  #pragma unroll
  for (int j=0;j<4;j++){
    const int col = cb + (wc<<6) + (j<<4) + lrow;
    const float bv = bias[col];
    #pragma unroll
    for (int i=0;i<4;i++){
      const int row0 = (rblk<<7) + (wr<<6) + (i<<4) + (lg<<2);
      #pragma unroll
      for (int r=0;r<4;r++){
        float v = acc[i][j][r] + bv;
        if (ACT) v = fmaxf(v, 0.f);
        OUT[(size_t)(row0+r)*512 + col] = f2b(v);
      }
    }
  }
}

// pdist: MODE 0 -> OUT f32 [b][k][m]. MODE 1 -> S2t f32 plane + SHL hi/lo bf16
// planes, transposed + XOR-granule-swizzled (key = planerow&15).
template<int MODE>
__global__ __launch_bounds__(256) void pdist_k(const u16* __restrict__ Xa,
    const u16* __restrict__ Xb2, const float* __restrict__ na, const float* __restrict__ nb,
    float* __restrict__ OUT, float* __restrict__ S2t, char* __restrict__ SHL){
  __shared__ __align__(16) u16 sA[128*64];
  __shared__ __align__(16) u16 sB[128*64];
  const int tid = threadIdx.x, wave = tid>>6, lane = tid&63;
  const int b = blockIdx.x;
  const u16* Ab = Xa + (size_t)b*(128*512);
  const u16* Bb = Xb2 + (size_t)b*(128*512);
  const int lrow = lane&15, lg = lane>>4, wr = wave>>1, wc = wave&1;
  f32x4 acc[4][4] = {};
  for (int s=0;s<8;s++){
    const int k0 = s<<6;
    #pragma unroll
    for (int q=0;q<4;q++){
      const int i = (wave<<2)+q;
      const int row = (i<<3) + (lane>>3);
      const int cd = (lane&7) ^ (row&7);
      gload_lds16(Ab + row*512 + k0 + (cd<<3), sA + i*512);
      gload_lds16(Bb + row*512 + k0 + (cd<<3), sB + i*512);
    }
    __syncthreads();
    #pragma unroll
    for (int kh=0;kh<2;kh++){
      bf16x8 a_[4], b_[4];
      #pragma unroll
      for (int i=0;i<4;i++){
        const int ra = (wr<<6)+(i<<4)+lrow;
        a_[i] = *(const bf16x8*)(sA + ra*64 + ((((kh<<2)+lg)^(ra&7))<<3));
        const int rb = (wc<<6)+(i<<4)+lrow;
        b_[i] = *(const bf16x8*)(sB + rb*64 + ((((kh<<2)+lg)^(rb&7))<<3));
      }
      #pragma unroll
      for (int i=0;i<4;i++)
        #pragma unroll
        for (int j=0;j<4;j++)
          acc[i][j] = __builtin_amdgcn_mfma_f32_16x16x32_bf16(a_[i], b_[j], acc[i][j], 0,0,0);
    }
    __syncthreads();
  }
  #pragma unroll
  for (int j=0;j<4;j++){
    const int col = (wc<<6)+(j<<4)+lrow;
    const float nbv = nb[b*128+col];
    #pragma unroll
    for (int i=0;i<4;i++){
      const int row0 = (wr<<6)+(i<<4)+(lg<<2);
      float sv[4];
      #pragma unroll
      for (int r=0;r<4;r++){
        float n2 = na[b*128+row0+r] + nbv - 2.0f*acc[i][j][r];
        sv[r] = sqrtf(fmaxf(n2, 1e-6f));
      }
      if (MODE==0){
        #pragma unroll
        for (int r=0;r<4;r++)
          OUT[(size_t)b*16384 + (size_t)(row0+r)*128 + col] = sv[r];
      } else {
        u16x4 hi4, lo4; f32x4 s2q;
        #pragma unroll
        for (int r=0;r<4;r++){
          u16 h = f2b(sv[r]); hi4[r] = h;
          lo4[r] = f2b(sv[r] - b2f(h));
          s2q[r] = sv[r]*sv[r];
        }
        const int sa = col*256 + ((((row0>>3)^col)&15)<<4) + ((row0&7)<<1);
        char* base = SHL + (size_t)b*65536;
        *(u16x4*)(base + sa) = hi4;
        *(u16x4*)(base + 32768 + sa) = lo4;
        *(f32x4*)(S2t + (size_t)b*16384 + col*128 + row0) = s2q;
      }
    }
  }
}

// ---------------------------------------------------------------------------
// mu/nu + their logs. 256 blocks x 128 threads.
__global__ void prep_k(const float* __restrict__ mask_q, const float* __restrict__ mask_r,
                       float* __restrict__ lmu, float* __restrict__ lnu,
                       float* __restrict__ mu, float* __restrict__ nu){
  int b = blockIdx.x, t = threadIdx.x;
  __shared__ float red[4];
  float mq = mask_q[b*128+t], mr = mask_r[b*128+t];
  float s1 = mq, s2 = mr;
  #pragma unroll
  for (int off=1;off<64;off<<=1){ s1 += __shfl_xor(s1,off); s2 += __shfl_xor(s2,off); }
  if ((t&63)==0){ red[t>>6] = s1; red[2+(t>>6)] = s2; }
  __syncthreads();
  float sumq = red[0]+red[1], sumr = red[2]+red[3];
  float muv = mq/(sumq+1e-8f), nuv = mr/(sumr+1e-8f);
  lmu[b*128+t] = __logf(fmaxf(muv,1e-8f));
  lnu[b*128+t] = __logf(fmaxf(nuv,1e-8f));
  mu[b*128+t] = muv;
  nu[b*128+t] = nuv;
}

// ---------------------------------------------------------------------------
// Entire 5-iter FGW loop. One 512-thread block per batch. Matmuls: split-bf16
// MFMA. Sinkhorn: dual register layouts —
//  Layout-R: thread (w,lg,l15) owns row kR=16w+l15, cols {16q+4lg+e}
//  Layout-C: same thread owns col nC=16w+l15, rows {16q+4lg+e}
// so each LSE pass is in-thread + 2 shfl, with one b32 broadcast via LDS.
__global__ __launch_bounds__(512,1) void fgw_loop_k(
    const char* __restrict__ SQHL, const char* __restrict__ SRHL,
    const float* __restrict__ SQ2, const float* __restrict__ SR2,
    const float* __restrict__ C_g,
    const float* __restrict__ MU, const float* __restrict__ NU,
    const float* __restrict__ LMU, const float* __restrict__ LNU,
    const float* __restrict__ log_eps,
    float* __restrict__ T_out, float* __restrict__ cost_out, float* __restrict__ sim_out)
{
  __shared__ __align__(16) char bufT[65536];   // T planes / TSr^T planes / lkP (row-major)
  __shared__ __align__(16) char bufS[65536];   // Sr planes / Sq planes / lkPT (col-major)
  __shared__ __align__(16) float avs[128], bvs[128], t1s[128], t2s[128];
  __shared__ __align__(16) float lus[128], lvs[128];
  __shared__ float redc[8];

  const int b = blockIdx.x, tid = threadIdx.x;
  const int w = tid>>6, lane = tid&63, l15 = lane&15, lg = lane>>4;
  const char* SqHLb = SQHL + (size_t)b*65536;
  const char* SrHLb = SRHL + (size_t)b*65536;
  const float* Sq2b = SQ2 + (size_t)b*16384;
  const float* Sr2b = SR2 + (size_t)b*16384;
  const float* Cb   = C_g + (size_t)b*16384;
  const float* MUb  = MU + b*128;
  const float* NUb  = NU + b*128;

  float eps = __expf(log_eps[0]); eps = fminf(fmaxf(eps,0.01f),0.5f);
  const float rho = 0.1f/(0.1f+eps), inve = 1.0f/eps;

  const int kR = 16*w + l15;       // Layout-R row
  const int nC = kR;               // Layout-C col
  const int n0 = 16*w + 4*lg;      // fragment-layout n base
  const float lmuR = LMU[b*128+kR];
  const float lnuC = LNU[b*128+nC];
  const float muR  = MUb[kR];
  const float nuC  = NUb[nC];

  // fragment A-row base + swizzle helpers (MFMA phases)
  const int rowA256 = (16*w + l15)*256;
  const int glo2 = lg ^ (l15 & 3);
  const int ghi2 = l15 & 12;
  const int wtail = l15*256 + ((((2*w + (lg>>1)) ^ l15)&15)<<4) + ((lg&1)<<3);

  f32x4 lkR[8], lkC[8];
  float luR = 0.f, lvC = 0.f;

  for (int outer=0; outer<5; outer++){
    // ---- prologue: stage Sr; build T planes + av/bv from lk (or mu x nu)
    #pragma unroll
    for (int r2=0;r2<8;r2++)
      gload_lds16(SrHLb + r2*8192 + tid*16, bufS + r2*8192 + tid*16);
    {
      f32x4 avp = {0.f,0.f,0.f,0.f};
      float bvp = 0.f;
      #pragma unroll
      for (int q=0;q<8;q++){
        f32x4 TRq, TCq;
        if (outer==0){
          const f32x4 nu4 = *(const f32x4*)(NUb + 16*q + 4*lg);
          const f32x4 mu4 = *(const f32x4*)(MUb + 16*q + 4*lg);
          TRq = muR*nu4;
          TCq = mu4*nuC;
        } else {
          const f32x4 lv4 = *(const f32x4*)&lvs[16*q+4*lg];
          const f32x4 lu4 = *(const f32x4*)&lus[16*q+4*lg];
          #pragma unroll
          for (int e=0;e<4;e++){
            TRq[e] = __expf(lkR[q][e] + luR + lv4[e]);
            TCq[e] = __expf(lkC[q][e] + lu4[e] + lvC);
          }
        }
        // T hi/lo plane write (row kR, col chunk 16q+4lg)
        u16x4 hi4, lo4;
        #pragma unroll
        for (int e=0;e<4;e++){
          u16 h = f2b(TRq[e]); hi4[e] = h;
          lo4[e] = f2b(TRq[e] - b2f(h));
        }
        const int sa = kR*256 + ((((2*q+(lg>>1)) ^ l15)&15)<<4) + ((lg&1)<<3);
        *(u16x4*)(bufT + sa) = hi4;
        *(u16x4*)(bufT + 32768 + sa) = lo4;
        avp += TRq;
        bvp += TCq[0]+TCq[1]+TCq[2]+TCq[3];
      }
      float av = avp[0]+avp[1]+avp[2]+avp[3];
      av += __shfl_xor(av,16); av += __shfl_xor(av,32);
      bvp += __shfl_xor(bvp,16); bvp += __shfl_xor(bvp,32);
      if (lg==0){ avs[kR] = av; bvs[nC] = bvp; }
    }
    __syncthreads();                           // Sr staged, planes + avs/bvs ready

    // ---- t1 = Sq^2 @ av, t2 = Sr^2 @ bv
    {
      const int k = tid>>2, q = tid&3;
      const float* r1 = Sq2b + k*128 + q*32;
      const float* r2p = Sr2b + k*128 + q*32;
      f32x4 a1 = {0.f,0.f,0.f,0.f}, a2 = {0.f,0.f,0.f,0.f};
      #pragma unroll
      for (int i=0;i<8;i++){
        a1 += (*(const f32x4*)(r1+4*i)) * (*(const f32x4*)(avs+q*32+4*i));
        a2 += (*(const f32x4*)(r2p+4*i)) * (*(const f32x4*)(bvs+q*32+4*i));
      }
      float s1 = a1[0]+a1[1]+a1[2]+a1[3];
      float s2 = a2[0]+a2[1]+a2[2]+a2[3];
      s1 += __shfl_xor(s1,1); s1 += __shfl_xor(s1,2);
      s2 += __shfl_xor(s2,1); s2 += __shfl_xor(s2,2);
      if (q==0){ t1s[k]=s1; t2s[k]=s2; }
    }
    // ---- phase A: TSr = T @ Sr
    f32x4 acc1[8] = {};
    #pragma unroll
    for (int qt=0;qt<4;qt++){
      const int colOff = (((4*qt) ^ ghi2) | glo2) << 4;
      const bf16x8 ahi = *(const bf16x8*)(bufT + rowA256 + colOff);
      const bf16x8 alo = *(const bf16x8*)(bufT + 32768 + rowA256 + colOff);
      const int bbase = l15*256 + colOff;
      #pragma unroll
      for (int nt=0;nt<8;nt++){
        const bf16x8 bhi = *(const bf16x8*)(bufS + nt*4096 + bbase);
        const bf16x8 blo = *(const bf16x8*)(bufS + 32768 + nt*4096 + bbase);
        acc1[nt] = __builtin_amdgcn_mfma_f32_16x16x32_bf16(ahi, bhi, acc1[nt], 0,0,0);
        acc1[nt] = __builtin_amdgcn_mfma_f32_16x16x32_bf16(ahi, blo, acc1[nt], 0,0,0);
        acc1[nt] = __builtin_amdgcn_mfma_f32_16x16x32_bf16(alo, bhi, acc1[nt], 0,0,0);
      }
    }
    __syncthreads();                           // phase A LDS reads complete
    // ---- stage Sq; write TSr^T hi/lo planes
    #pragma unroll
    for (int r2=0;r2<8;r2++)
      gload_lds16(SqHLb + r2*8192 + tid*16, bufS + r2*8192 + tid*16);
    #pragma unroll
    for (int nt=0;nt<8;nt++){
      u16x4 hi4, lo4;
      #pragma unroll
      for (int r=0;r<4;r++){
        u16 h = f2b(acc1[nt][r]); hi4[r] = h;
        lo4[r] = f2b(acc1[nt][r] - b2f(h));
      }
      const int sa = nt*4096 + wtail;
      *(u16x4*)(bufT + sa) = hi4;
      *(u16x4*)(bufT + 32768 + sa) = lo4;
    }
    __syncthreads();                           // Sq staged + TSr^T planes ready
    // ---- phase B: G^T = TSr^T @ Sq
    f32x4 acc2[8] = {};
    #pragma unroll
    for (int qt=0;qt<4;qt++){
      const int colOff = (((4*qt) ^ ghi2) | glo2) << 4;
      const bf16x8 ahi = *(const bf16x8*)(bufT + rowA256 + colOff);
      const bf16x8 alo = *(const bf16x8*)(bufT + 32768 + rowA256 + colOff);
      const int bbase = l15*256 + colOff;
      #pragma unroll
      for (int kt=0;kt<8;kt++){
        const bf16x8 bhi = *(const bf16x8*)(bufS + kt*4096 + bbase);
        const bf16x8 blo = *(const bf16x8*)(bufS + 32768 + kt*4096 + bbase);
        acc2[kt] = __builtin_amdgcn_mfma_f32_16x16x32_bf16(ahi, bhi, acc2[kt], 0,0,0);
        acc2[kt] = __builtin_amdgcn_mfma_f32_16x16x32_bf16(ahi, blo, acc2[kt], 0,0,0);
        acc2[kt] = __builtin_amdgcn_mfma_f32_16x16x32_bf16(alo, bhi, acc2[kt], 0,0,0);
      }
    }
    // ---- lk (fragment layout) = -(0.5C + 0.5(t1 + t2 - 2G))/eps
    f32x4 lkf[8];
    {
      const f32x4 t24 = *(const f32x4*)&t2s[n0];
      #pragma unroll
      for (int kt=0;kt<8;kt++){
        const int k = 16*kt + l15;
        const f32x4 c4 = *(const f32x4*)(Cb + k*128 + n0);
        lkf[kt] = -inve*(0.5f*c4 + 0.5f*(t1s[k] + t24 - 2.0f*acc2[kt]));
      }
    }
    __syncthreads();                           // all phase-B LDS reads done
    // ---- bounce lk into row-major (bufT) and col-major (bufS) f32 planes
    #pragma unroll
    for (int kt=0;kt<8;kt++){
      const int row = 16*kt + l15;
      const int gp = ((4*w+lg) ^ (row&31)) & 31;
      *(f32x4*)(bufT + row*512 + gp*16) = lkf[kt];
      #pragma unroll
      for (int e=0;e<4;e++){
        const int n = n0 + e;
        const int gt = ((4*kt + (l15>>2)) ^ (n&31)) & 31;
        *(float*)(bufS + n*512 + gt*16 + (l15&3)*4) = lkf[kt][e];
      }
    }
    __syncthreads();
    #pragma unroll
    for (int q=0;q<8;q++){
      const int g1 = ((4*q+lg) ^ (kR&31)) & 31;
      lkR[q] = *(const f32x4*)(bufT + kR*512 + g1*16);
      const int g2 = ((4*q+lg) ^ (nC&31)) & 31;
      lkC[q] = *(const f32x4*)(bufS + nC*512 + g2*16);
    }
    // ---- Sinkhorn: 10 iterations (2 barriers each)
    for (int it=0; it<10; it++){
      // u-pass (Layout-R): lse over n
      f32x4 y[8];
      #pragma unroll
      for (int q=0;q<8;q++){
        if (it==0) y[q] = lkR[q];
        else       y[q] = lkR[q] + *(const f32x4*)&lvs[16*q+4*lg];
      }
      f32x4 m4 = y[0];
      #pragma unroll
      for (int q=1;q<8;q++) m4 = vmax4(m4, y[q]);
      float mx = fmaxf(fmaxf(m4[0],m4[1]), fmaxf(m4[2],m4[3]));
      mx = fmaxf(mx, __shfl_xor(mx,16));
      mx = fmaxf(mx, __shfl_xor(mx,32));
      f32x4 s4 = {0.f,0.f,0.f,0.f};
      #pragma unroll
      for (int q=0;q<8;q++){
        #pragma unroll
        for (int e=0;e<4;e++) s4[e] += __expf(y[q][e]-mx);
      }
      float s = s4[0]+s4[1]+s4[2]+s4[3];
      s += __shfl_xor(s,16); s += __shfl_xor(s,32);
      luR = rho*(lmuR - (mx + __logf(s)));
      if (lg==0) lus[kR] = luR;
      __syncthreads();
      // v-pass (Layout-C): lse over k
      #pragma unroll
      for (int q=0;q<8;q++)
        y[q] = lkC[q] + *(const f32x4*)&lus[16*q+4*lg];
      m4 = y[0];
      #pragma unroll
      for (int q=1;q<8;q++) m4 = vmax4(m4, y[q]);
      mx = fmaxf(fmaxf(m4[0],m4[1]), fmaxf(m4[2],m4[3]));
      mx = fmaxf(mx, __shfl_xor(mx,16));
      mx = fmaxf(mx, __shfl_xor(mx,32));
      s4 = (f32x4){0.f,0.f,0.f,0.f};
      #pragma unroll
      for (int q=0;q<8;q++){
        #pragma unroll
        for (int e=0;e<4;e++) s4[e] += __expf(y[q][e]-mx);
      }
      s = s4[0]+s4[1]+s4[2]+s4[3];
      s += __shfl_xor(s,16); s += __shfl_xor(s,32);
      lvC = rho*(lnuC - (mx + __logf(s)));
      if (lg==0) lvs[nC] = lvC;
      __syncthreads();
    }
    // ---- final outer: T out + cost/sim
    if (outer==4){
      float cp = 0.f;
      float* Tb = T_out + (size_t)b*16384;
      #pragma unroll
      for (int q=0;q<8;q++){
        const f32x4 lv4 = *(const f32x4*)&lvs[16*q+4*lg];
        f32x4 t;
        #pragma unroll
        for (int e=0;e<4;e++) t[e] = __expf(lkR[q][e] + luR + lv4[e]);
        *(f32x4*)(Tb + kR*128 + 16*q + 4*lg) = t;
        const f32x4 p = t*lkR[q];
        cp += p[0]+p[1]+p[2]+p[3];
      }
      cp *= -eps;
      #pragma unroll
      for (int off=1;off<64;off<<=1) cp += __shfl_xor(cp, off);
      if (lane==0) redc[w] = cp;
      __syncthreads();
      if (tid==0){
        float tot = 0.f;
        #pragma unroll
        for (int w2=0;w2<8;w2++) tot += redc[w2];
        cost_out[b] = tot;
        sim_out[b]  = 1.0f/(1.0f + __expf(tot));
      }
    }
  }
}

// ---------------------------------------------------------------------------
extern "C" void kernel_launch(void* const* d_in, const int* in_sizes, int n_in,
                              void* d_out, int out_size, void* d_ws, size_t ws_size,
                              hipStream_t stream){
  const float* sq      = (const float*)d_in[0];
  const float* sr      = (const float*)d_in[1];
  const float* mask_q  = (const float*)d_in[2];
  const float* mask_r  = (const float*)d_in[3];
  const float* cq      = (const float*)d_in[4];
  const float* cr      = (const float*)d_in[5];
  const float* W1      = (const float*)d_in[6];
  const float* b1      = (const float*)d_in[7];
  const float* W2      = (const float*)d_in[8];
  const float* b2      = (const float*)d_in[9];
  const float* log_eps = (const float*)d_in[10];

  float* out  = (float*)d_out;
  float* sim  = out;                 // [256]
  float* Tm   = out + 256;           // [256][128][128]
  float* Cm   = Tm + 4194304;        // [256][128][128]
  float* cost = Cm + 4194304;        // [256]

  char* ws = (char*)d_ws;
  size_t off = 0;
  auto alloc = [&](size_t bytes)->void*{ void* p = ws + off; off += (bytes+255)&~(size_t)255; return p; };
  u16*   SQB = (u16*)  alloc(33554432);   // sq bf16 -> Pq rows 0..32767 -> plane region
  u16*   SRB = (u16*)  alloc(33554432);   // sr bf16 -> Pq rows 32768..65535 -> plane region
  u16*   HQ  = (u16*)  alloc(33554432);   // hidden q -> cq bf16
  u16*   HR  = (u16*)  alloc(33554432);   // hidden r -> cr bf16
  u16*   W1T = (u16*)  alloc(524288);
  u16*   W2T = (u16*)  alloc(524288);
  float* NP  = (float*)alloc(262144);     // norms of P rows (65536)
  float* NCQ = (float*)alloc(131072);
  float* NCR = (float*)alloc(131072);
  float* LMU = (float*)alloc(131072);
  float* LNU = (float*)alloc(131072);
  float* MUA = (float*)alloc(131072);
  float* NUA = (float*)alloc(131072);
  (void)ws_size; (void)in_sizes; (void)n_in; (void)out_size;

  u16* PQ  = SQB;          // gemm2 output (65536 rows, spans SQB+SRB)
  u16* CQB = HQ;
  u16* CRB = HR;

  // After pdist#1 consumes PQ, its 64MB region is reused for the loop planes:
  float* SQ2  = (float*)((char*)SQB);                 // 16MB f32  Sq^2
  float* SR2  = (float*)((char*)SQB + 16777216);      // 16MB f32  Sr^2
  char*  SQHL = (char*)SQB + 33554432;                // 16MB bf16 hi/lo Sq planes
  char*  SRHL = (char*)SQB + 50331648;                // 16MB bf16 hi/lo Sr planes

  prepw_k<<<1024,256,0,stream>>>(W1, W1T);
  prepw_k<<<1024,256,0,stream>>>(W2, W2T);
  cvt_k<<<8192,256,0,stream>>>(sq, SQB, nullptr, 32768);
  cvt_k<<<8192,256,0,stream>>>(sr, SRB, nullptr, 32768);
  gemm_k<1><<<2048,256,0,stream>>>(SQB, W1T, b1, HQ);   // H = relu(X@W1+b1)
  gemm_k<0><<<2048,256,0,stream>>>(HQ, W2T, b2, PQ);    // P = H@W2+b2
  normb_k<<<16384,256,0,stream>>>(PQ, NP, 65536);
  cvt_k<<<8192,256,0,stream>>>(cq, CQB, NCQ, 32768);
  cvt_k<<<8192,256,0,stream>>>(cr, CRB, NCR, 32768);
  pdist_k<0><<<256,256,0,stream>>>(PQ, PQ + (size_t)32768*512, NP, NP + 32768,
                                   Cm, nullptr, nullptr);
  pdist_k<1><<<256,256,0,stream>>>(CQB, CQB, NCQ, NCQ, nullptr, SQ2, SQHL);
  pdist_k<1><<<256,256,0,stream>>>(CRB, CRB, NCR, NCR, nullptr, SR2, SRHL);
  prep_k<<<256,128,0,stream>>>(mask_q, mask_r, LMU, LNU, MUA, NUA);
  fgw_loop_k<<<256,512,0,stream>>>(SQHL, SRHL, SQ2, SR2, Cm, MUA, NUA, LMU, LNU,
                                   log_eps, Tm, cost, sim);
}